// Round 4
// baseline (28.901 us; speedup 1.0000x reference)
//
#include <hip/hip_runtime.h>
#include <math.h>

#define NPTS 2048
#define NBATCH 8
#define NC (NBATCH * NPTS)
#define COUT 9
#define CELLS 1000        // 10x10x10 grid, cell width 1/9.99 > RADIUS with margin
#define SCALE 65536.0f
#define CAND_MAX 256
#define K4_WPB 4

// ---------------- ws layout (bytes) ----------------
// [0,       262144)  float4 sorted4[16384]
// [262144,  327680)  int    sortedIdx[16384]
// [327680,  359680)  int    counts[8000]      (zeroed each call)
// [359680,  391712)  int    starts[8*1001]
// [391712,  423712)  int    ticket[8000]
// [423712,  489248)  int    cellOf[16384]

__global__ __launch_bounds__(256) void k1_count(const float* __restrict__ pts,
                                                int* __restrict__ counts,
                                                int* __restrict__ cellOf) {
    const int idx = blockIdx.x * 256 + threadIdx.x;
    if (idx >= NC) return;
    const float x = pts[idx * 3 + 0], y = pts[idx * 3 + 1], z = pts[idx * 3 + 2];
    const int cx = (int)(x * 9.99f), cy = (int)(y * 9.99f), cz = (int)(z * 9.99f);
    const int cid = (cx * 10 + cy) * 10 + cz;
    cellOf[idx] = cid;
    atomicAdd(&counts[(idx >> 11) * CELLS + cid], 1);
}

__global__ __launch_bounds__(256) void k2_scan(const int* __restrict__ counts,
                                               int* __restrict__ starts,
                                               int* __restrict__ ticket) {
    const int b = blockIdx.x;          // one block per batch
    const int t = threadIdx.x;
    const int lane = t & 63, wv = t >> 6;
    const int c0 = t * 4;              // 4 cells per thread; 1000 % 4 == 0
    const int* cnt = counts + b * CELLS;
    int v0 = 0, v1 = 0, v2 = 0, v3 = 0;
    if (c0 < CELLS) { v0 = cnt[c0]; v1 = cnt[c0 + 1]; v2 = cnt[c0 + 2]; v3 = cnt[c0 + 3]; }
    const int s = v0 + v1 + v2 + v3;
    int scan = s;
    #pragma unroll
    for (int off = 1; off < 64; off <<= 1) {
        const int n = __shfl_up(scan, off);
        if (lane >= off) scan += n;
    }
    __shared__ int wtot[4];
    if (lane == 63) wtot[wv] = scan;
    __syncthreads();
    int wbase = 0;
    for (int k = 0; k < wv; ++k) wbase += wtot[k];
    int excl = wbase + scan - s;       // exclusive prefix of this thread's 4 cells
    if (c0 < CELLS) {
        int* st = starts + b * 1001;
        int* tk = ticket + b * CELLS;
        st[c0]     = excl; tk[c0]     = excl; excl += v0;
        st[c0 + 1] = excl; tk[c0 + 1] = excl; excl += v1;
        st[c0 + 2] = excl; tk[c0 + 2] = excl; excl += v2;
        st[c0 + 3] = excl; tk[c0 + 3] = excl; excl += v3;
    }
    if (t == 0) starts[b * 1001 + 1000] = NPTS;
}

__global__ __launch_bounds__(256) void k3_scatter(const float* __restrict__ pts,
                                                  const float* __restrict__ attrs,
                                                  const int* __restrict__ cellOf,
                                                  int* __restrict__ ticket,
                                                  float4* __restrict__ sorted4,
                                                  int* __restrict__ sortedIdx) {
    const int idx = blockIdx.x * 256 + threadIdx.x;
    if (idx >= NC) return;
    const int b = idx >> 11;
    const int cid = cellOf[idx];
    const int pos = atomicAdd(&ticket[b * CELLS + cid], 1);
    const int dst = b * NPTS + pos;
    sorted4[dst] = make_float4(pts[idx * 3 + 0], pts[idx * 3 + 1], pts[idx * 3 + 2],
                               attrs[idx]);
    sortedIdx[dst] = idx & (NPTS - 1);
}

__global__ __launch_bounds__(256) void k4_main(const float4* __restrict__ sorted4,
                                               const int* __restrict__ sortedIdx,
                                               const int* __restrict__ starts,
                                               const float* __restrict__ cw,
                                               const float* __restrict__ cb,
                                               float* __restrict__ out) {
    const int lane = threadIdx.x & 63;
    const int w = threadIdx.x >> 6;
    const int wid = blockIdx.x * K4_WPB + w;       // [0, 8000): one wave per grid cell
    const int b = wid / CELLS;
    const int cid = wid - b * CELLS;
    const int* st = starts + b * 1001;

    const int cstart = st[cid];
    const int cend   = st[cid + 1];
    if (cstart >= cend) return;                    // no centers in this cell

    // Exact float thresholds (validated R2/R3):
    //   sqrt_rn(d2) <= 0.1f   <=>  d2 <= T1
    //   trunc(dist/0.05f)>=1  <=>  dist >= 0.05f  <=>  d2 >= T2
    constexpr double MIDR   = 26843547.0 / 268435456.0;   // (0.1f + next)/2, exact
    constexpr double MIDR2  = MIDR * MIDR;
    constexpr double MID2   = 26843545.0 / 536870912.0;   // (prev + 0.05f)/2, exact
    constexpr double MID2SQ = MID2 * MID2;
    float T1 = (float)MIDR2;  if ((double)T1 >= MIDR2)  T1 = nextafterf(T1, 0.0f);
    float T2 = (float)MID2SQ; if ((double)T2 <= MID2SQ) T2 = nextafterf(T2, 1.0f);

    // conv weights: lane o<9 holds cw[o][0..15]
    float cwreg[16];
    float bias = 0.0f;
    if (lane < COUT) {
        bias = cb[lane];
        #pragma unroll
        for (int q = 0; q < 16; ++q) cwreg[q] = cw[lane * 16 + q];
    }

    // 9 neighbor (x,y) columns, each a contiguous z-run in the sorted order
    const int cx = cid / 100, cy = (cid / 10) % 10, cz = cid % 10;
    int rs = 0, len = 0;
    if (lane < 9) {
        const int nx = cx + (lane / 3) - 1, ny = cy + (lane % 3) - 1;
        if (nx >= 0 && nx < 10 && ny >= 0 && ny < 10) {
            const int zlo = cz > 0 ? cz - 1 : 0;
            const int zhi = cz < 9 ? cz + 1 : 9;
            const int base = (nx * 10 + ny) * 10;
            rs  = st[base + zlo];
            len = st[base + zhi + 1] - rs;
        }
    }
    int scan = len;                                 // exclusive prefix over 9 lanes
    #pragma unroll
    for (int off = 1; off < 16; off <<= 1) {
        const int n = __shfl_up(scan, off);
        if (lane >= off) scan += n;
    }
    const int T   = __shfl(scan, 8);
    const int pre = scan - len;

    __shared__ int s_cand[K4_WPB][CAND_MAX];
    if (lane < 9) {
        int p = pre;
        for (int k = 0; k < len; ++k) {
            if (p < CAND_MAX) s_cand[w][p] = rs + k;
            ++p;
        }
    }
    const int Tc = T < CAND_MAX ? T : CAND_MAX;     // Poisson(55): never clips here

    const float4* sb4 = sorted4 + b * NPTS;

    __shared__ int s_sum[K4_WPB][4][16];            // fixed-point Q16 bins
    __shared__ int s_cnt[K4_WPB][4][16];

    for (int g0 = cstart; g0 < cend; g0 += 4) {     // center groups of 4
        const int ng = min(4, cend - g0);
        s_sum[w][lane >> 4][lane & 15] = 0;         // 64 bins == 64 lanes
        s_cnt[w][lane >> 4][lane & 15] = 0;

        const float4 cc0 = sb4[g0];
        const float4 cc1 = ng > 1 ? sb4[g0 + 1] : cc0;
        const float4 cc2 = ng > 2 ? sb4[g0 + 2] : cc0;
        const float4 cc3 = ng > 3 ? sb4[g0 + 3] : cc0;

        for (int c0 = 0; c0 < Tc; c0 += 64) {
            const int g = c0 + lane;
            const bool act = g < Tc;
            const int j = act ? s_cand[w][g] : s_cand[w][0];
            const float4 pj = sb4[j];
            const int av = __float2int_rn(pj.w * SCALE);
            #pragma unroll
            for (int c = 0; c < 4; ++c) {
                if (c >= ng) break;
                const float4 cc = (c == 0) ? cc0 : (c == 1) ? cc1 : (c == 2) ? cc2 : cc3;
                // strict IEEE, matches numpy (x*x + y*y) + z*z
                const float dx = __fsub_rn(cc.x, pj.x);
                const float dy = __fsub_rn(cc.y, pj.y);
                const float dz = __fsub_rn(cc.z, pj.z);
                const float d2 = __fadd_rn(__fadd_rn(__fmul_rn(dx, dx), __fmul_rn(dy, dy)),
                                           __fmul_rn(dz, dz));
                if (act && d2 <= T1) {
                    const int oct = (dx >= 0.0f ? 1 : 0) + (dy >= 0.0f ? 2 : 0)
                                  + (dz >= 0.0f ? 4 : 0);
                    const int cell = (d2 >= T2 ? 8 : 0) + oct;
                    atomicAdd(&s_sum[w][c][cell], av);
                    atomicAdd(&s_cnt[w][c][cell], 1);
                }
            }
        }

        #pragma unroll
        for (int c = 0; c < 4; ++c) {               // epilogue per center
            if (c >= ng) break;
            float mv = 0.0f;
            if (lane < 16) {
                const int ssum = s_sum[w][c][lane];
                const int scnt = s_cnt[w][c][lane];
                mv = ((float)ssum * (1.0f / SCALE)) / (float)(scnt ? scnt : 1);
            }
            float acc = bias;
            #pragma unroll
            for (int q = 0; q < 16; ++q) acc = fmaf(__shfl(mv, q), cwreg[q], acc);
            const int orig = sortedIdx[b * NPTS + g0 + c];
            if (lane < COUT) out[(size_t)(b * NPTS + orig) * COUT + lane] = acc;
        }
    }
}

extern "C" void kernel_launch(void* const* d_in, const int* in_sizes, int n_in,
                              void* d_out, int out_size, void* d_ws, size_t ws_size,
                              hipStream_t stream) {
    const float* pts   = (const float*)d_in[0];  // [8,2048,3]
    const float* attrs = (const float*)d_in[1];  // [8,2048,1]
    const float* cw    = (const float*)d_in[2];  // [9,1,16]
    const float* cb    = (const float*)d_in[3];  // [9]
    float* out = (float*)d_out;                  // [8,2048,9]

    char* ws = (char*)d_ws;
    float4* sorted4   = (float4*)(ws);
    int*    sortedIdx = (int*)(ws + 262144);
    int*    counts    = (int*)(ws + 327680);
    int*    starts    = (int*)(ws + 359680);
    int*    ticket    = (int*)(ws + 391712);
    int*    cellOf    = (int*)(ws + 423712);

    hipMemsetAsync(counts, 0, 8000 * sizeof(int), stream);
    k1_count  <<<NC / 256, 256, 0, stream>>>(pts, counts, cellOf);
    k2_scan   <<<NBATCH, 256, 0, stream>>>(counts, starts, ticket);
    k3_scatter<<<NC / 256, 256, 0, stream>>>(pts, attrs, cellOf, ticket, sorted4, sortedIdx);
    k4_main   <<<(NBATCH * CELLS) / K4_WPB, 256, 0, stream>>>(sorted4, sortedIdx, starts,
                                                              cw, cb, out);
}

// Round 5
// 21.744 us; speedup vs baseline: 1.3292x; 1.3292x over previous
//
#include <hip/hip_runtime.h>
#include <math.h>

#define NPTS 2048
#define NBATCH 8
#define NC (NBATCH * NPTS)
#define COUT 9
#define CELLS 1000        // 10x10x10 grid; width 1/9.99 = 0.1001 > radius + fp margin
#define SCALE 65536.0f
#define CAND_MAX 256
#define WPB 4

// ---------------- ws layout (bytes) ----------------
// [0,       262144)  float4 sorted4[16384]
// [262144,  327680)  int    sortedIdx[16384]
// [327680,  359712)  int    starts[8*1001]

// ---- kernel A: per-batch LDS counting sort (histogram -> scan -> scatter) ----
__global__ __launch_bounds__(1024) void sort_kernel(
    const float* __restrict__ pts, const float* __restrict__ attrs,
    float4* __restrict__ sorted4, int* __restrict__ sortedIdx,
    int* __restrict__ starts)
{
    const int b = blockIdx.x;           // one block per batch
    const int t = threadIdx.x;
    const int lane = t & 63, wv = t >> 6;

    __shared__ int hist[CELLS];         // histogram, then reused as scatter tickets
    __shared__ int wt[16];

    if (t < CELLS) hist[t] = 0;
    __syncthreads();

    const float* pb = pts   + (size_t)b * NPTS * 3;
    const float* ab = attrs + (size_t)b * NPTS;

    // two points per thread
    const int i0 = t, i1 = t + 1024;
    const float4 p0 = make_float4(pb[i0*3], pb[i0*3+1], pb[i0*3+2], ab[i0]);
    const float4 p1 = make_float4(pb[i1*3], pb[i1*3+1], pb[i1*3+2], ab[i1]);
    const int cid0 = ((int)(p0.x*9.99f)*10 + (int)(p0.y*9.99f))*10 + (int)(p0.z*9.99f);
    const int cid1 = ((int)(p1.x*9.99f)*10 + (int)(p1.y*9.99f))*10 + (int)(p1.z*9.99f);
    atomicAdd(&hist[cid0], 1);
    atomicAdd(&hist[cid1], 1);
    __syncthreads();

    // block-wide exclusive scan over 1000 cell counts (thread t owns cell t)
    const int v = (t < CELLS) ? hist[t] : 0;
    int sc = v;
    #pragma unroll
    for (int off = 1; off < 64; off <<= 1) {
        const int n = __shfl_up(sc, off);
        if (lane >= off) sc += n;
    }
    if (lane == 63) wt[wv] = sc;
    __syncthreads();
    int wbase = 0;
    #pragma unroll
    for (int k = 0; k < 16; ++k) { const int x = wt[k]; if (k < wv) wbase += x; }
    const int excl = wbase + sc - v;
    __syncthreads();                    // everyone has read hist; safe to overwrite
    if (t < CELLS) {
        starts[b * 1001 + t] = excl;
        hist[t] = excl;                 // reuse as ticket counter
    }
    if (t == 0) starts[b * 1001 + 1000] = NPTS;
    __syncthreads();

    // scatter (order nondeterministic within a cell; per-cell SETS deterministic,
    // and all downstream accumulation is commutative integer -> output bit-stable)
    int pos = atomicAdd(&hist[cid0], 1);
    sorted4[b*NPTS + pos] = p0; sortedIdx[b*NPTS + pos] = i0;
    pos = atomicAdd(&hist[cid1], 1);
    sorted4[b*NPTS + pos] = p1; sortedIdx[b*NPTS + pos] = i1;
}

// ---- kernel B: one wave per grid cell ----
__global__ __launch_bounds__(256) void main_kernel(
    const float4* __restrict__ sorted4, const int* __restrict__ sortedIdx,
    const int* __restrict__ starts, const float* __restrict__ cw,
    const float* __restrict__ cb, float* __restrict__ out)
{
    const int lane = threadIdx.x & 63;
    const int w = threadIdx.x >> 6;
    const int wid = blockIdx.x * WPB + w;          // [0, 8000)
    const int b = wid / CELLS;
    const int cid = wid - b * CELLS;
    const int* st = starts + b * 1001;

    const int cstart = st[cid];
    const int cend   = st[cid + 1];
    if (cstart >= cend) return;

    // Exact float thresholds (validated R2-R4):
    //   sqrt_rn(d2) <= 0.1f   <=>  d2 <= T1
    //   trunc(dist/0.05f)>=1  <=>  dist >= 0.05f  <=>  d2 >= T2
    constexpr double MIDR   = 26843547.0 / 268435456.0;
    constexpr double MIDR2  = MIDR * MIDR;
    constexpr double MID2   = 26843545.0 / 536870912.0;
    constexpr double MID2SQ = MID2 * MID2;
    float T1 = (float)MIDR2;  if ((double)T1 >= MIDR2)  T1 = nextafterf(T1, 0.0f);
    float T2 = (float)MID2SQ; if ((double)T2 <= MID2SQ) T2 = nextafterf(T2, 1.0f);

    float cwreg[16];
    float bias = 0.0f;
    if (lane < COUT) {
        bias = cb[lane];
        #pragma unroll
        for (int q = 0; q < 16; ++q) cwreg[q] = cw[lane * 16 + q];
    }

    // 9 stencil (x,y) columns; each a contiguous z-run in sorted order
    const int cx = cid / 100, cy = (cid / 10) % 10, cz = cid % 10;
    int rs = 0, len = 0;
    if (lane < 9) {
        const int nx = cx + (lane / 3) - 1, ny = cy + (lane % 3) - 1;
        if (nx >= 0 && nx < 10 && ny >= 0 && ny < 10) {
            const int zlo = cz > 0 ? cz - 1 : 0;
            const int zhi = cz < 9 ? cz + 1 : 9;
            const int base = (nx * 10 + ny) * 10;
            rs  = st[base + zlo];
            len = st[base + zhi + 1] - rs;
        }
    }
    int sc = len;
    #pragma unroll
    for (int off = 1; off < 16; off <<= 1) {
        const int n = __shfl_up(sc, off);
        if (lane >= off) sc += n;
    }
    const int T   = __shfl(sc, 8);
    const int pre = sc - len;

    // broadcast run descriptors to all lanes (registers, fully unrolled)
    int rs_a[9], pre_a[9];
    #pragma unroll
    for (int r = 0; r < 9; ++r) { rs_a[r] = __shfl(rs, r); pre_a[r] = __shfl(pre, r); }

    // parallel compaction: all 64 lanes build the candidate index list
    __shared__ int s_cand[WPB][CAND_MAX];
    for (int idx = lane; idx < T; idx += 64) {
        int r = 0;
        #pragma unroll
        for (int rr = 1; rr < 9; ++rr) if (idx >= pre_a[rr]) r = rr;  // last run with pre<=idx
        s_cand[w][idx] = rs_a[r] + (idx - pre_a[r]);
    }
    const int Tc = T < CAND_MAX ? T : CAND_MAX;    // mean 55, never clips

    const float4* sb4 = sorted4 + b * NPTS;

    __shared__ int s_sum[WPB][4][16];              // fixed-point Q16 bins
    __shared__ int s_cnt[WPB][4][16];

    for (int g0 = cstart; g0 < cend; g0 += 4) {
        const int ng = min(4, cend - g0);
        s_sum[w][lane >> 4][lane & 15] = 0;
        s_cnt[w][lane >> 4][lane & 15] = 0;

        const float4 cc0 = sb4[g0];
        const float4 cc1 = ng > 1 ? sb4[g0 + 1] : cc0;
        const float4 cc2 = ng > 2 ? sb4[g0 + 2] : cc0;
        const float4 cc3 = ng > 3 ? sb4[g0 + 3] : cc0;

        for (int c0 = 0; c0 < Tc; c0 += 64) {
            const int g = c0 + lane;
            const bool act = g < Tc;
            const int j = act ? s_cand[w][g] : s_cand[w][0];
            const float4 pj = sb4[j];
            const int av = __float2int_rn(pj.w * SCALE);
            #pragma unroll
            for (int c = 0; c < 4; ++c) {
                if (c >= ng) break;
                const float4 cc = (c == 0) ? cc0 : (c == 1) ? cc1 : (c == 2) ? cc2 : cc3;
                // strict IEEE, matches numpy (x*x + y*y) + z*z
                const float dx = __fsub_rn(cc.x, pj.x);
                const float dy = __fsub_rn(cc.y, pj.y);
                const float dz = __fsub_rn(cc.z, pj.z);
                const float d2 = __fadd_rn(__fadd_rn(__fmul_rn(dx, dx), __fmul_rn(dy, dy)),
                                           __fmul_rn(dz, dz));
                if (act && d2 <= T1) {
                    const int oct = (dx >= 0.0f ? 1 : 0) + (dy >= 0.0f ? 2 : 0)
                                  + (dz >= 0.0f ? 4 : 0);
                    const int cell = (d2 >= T2 ? 8 : 0) + oct;
                    atomicAdd(&s_sum[w][c][cell], av);
                    atomicAdd(&s_cnt[w][c][cell], 1);
                }
            }
        }

        #pragma unroll
        for (int c = 0; c < 4; ++c) {
            if (c >= ng) break;
            float mv = 0.0f;
            if (lane < 16) {
                const int ssum = s_sum[w][c][lane];
                const int scnt = s_cnt[w][c][lane];
                mv = ((float)ssum * (1.0f / SCALE)) / (float)(scnt ? scnt : 1);
            }
            float acc = bias;
            #pragma unroll
            for (int q = 0; q < 16; ++q) acc = fmaf(__shfl(mv, q), cwreg[q], acc);
            const int orig = sortedIdx[b * NPTS + g0 + c];
            if (lane < COUT) out[(size_t)(b * NPTS + orig) * COUT + lane] = acc;
        }
    }
}

extern "C" void kernel_launch(void* const* d_in, const int* in_sizes, int n_in,
                              void* d_out, int out_size, void* d_ws, size_t ws_size,
                              hipStream_t stream) {
    const float* pts   = (const float*)d_in[0];  // [8,2048,3]
    const float* attrs = (const float*)d_in[1];  // [8,2048,1]
    const float* cw    = (const float*)d_in[2];  // [9,1,16]
    const float* cb    = (const float*)d_in[3];  // [9]
    float* out = (float*)d_out;                  // [8,2048,9]

    char* ws = (char*)d_ws;
    float4* sorted4   = (float4*)(ws);
    int*    sortedIdx = (int*)(ws + 262144);
    int*    starts    = (int*)(ws + 327680);

    sort_kernel<<<NBATCH, 1024, 0, stream>>>(pts, attrs, sorted4, sortedIdx, starts);
    main_kernel<<<(NBATCH * CELLS) / WPB, 256, 0, stream>>>(sorted4, sortedIdx, starts,
                                                            cw, cb, out);
}

// Round 6
// 19.830 us; speedup vs baseline: 1.4575x; 1.0965x over previous
//
#include <hip/hip_runtime.h>
#include <math.h>

#define NPTS 2048
#define NBATCH 8
#define NC (NBATCH * NPTS)
#define COUT 9
#define WPB 4    // waves per block
#define CPW 2    // centers per wave
#define SCALE 65536.0f

// ONE dispatch total: per-replay fixed cost (graph submit + inter-node drain)
// dominates at this problem size, so node count is the lever. Brute-force
// pair sweep with wave-private LDS bins; exact-threshold math validated R2-R5.
__global__ __launch_bounds__(256) void pconv_fused(
    const float* __restrict__ pts,    // [B,N,3]
    const float* __restrict__ attrs,  // [B,N,1]
    const float* __restrict__ cw,     // [COUT,1,16] flat
    const float* __restrict__ cb,     // [COUT]
    float* __restrict__ out)          // [B,N,COUT]
{
    const int lane = threadIdx.x & 63;
    const int w    = threadIdx.x >> 6;
    const int wid  = blockIdx.x * WPB + w;
    const int ci0  = wid * CPW;               // 2 consecutive centers, same batch
    const int b    = ci0 >> 11;
    const int i0   = ci0 & (NPTS - 1);

    __shared__ int   s_sum[WPB][CPW][16];     // fixed-point Q16
    __shared__ int   s_cnt[WPB][CPW][16];
    __shared__ float s_mean[WPB][CPW][16];

    if (lane < CPW * 16) {
        s_sum[w][lane >> 4][lane & 15] = 0;
        s_cnt[w][lane >> 4][lane & 15] = 0;
    }

    // Exact float thresholds reproducing reference semantics (validated R2-R5):
    //   sqrt_rn(d2) <= 0.1f    <=>  d2 <= T1
    //   trunc(dist/0.05f) >= 1 <=>  dist >= 0.05f  <=>  d2 >= T2
    constexpr double MIDR   = 26843547.0 / 268435456.0;   // (0.1f + next)/2, exact
    constexpr double MIDR2  = MIDR * MIDR;
    constexpr double MID2   = 26843545.0 / 536870912.0;   // (prev + 0.05f)/2, exact
    constexpr double MID2SQ = MID2 * MID2;
    float T1 = (float)MIDR2;  if ((double)T1 >= MIDR2)  T1 = nextafterf(T1, 0.0f);
    float T2 = (float)MID2SQ; if ((double)T2 <= MID2SQ) T2 = nextafterf(T2, 1.0f);

    const float* pb = pts   + (size_t)b * NPTS * 3;
    const float* ab = attrs + (size_t)b * NPTS;

    const float cx0 = pb[i0 * 3 + 0], cy0 = pb[i0 * 3 + 1], cz0 = pb[i0 * 3 + 2];
    const float cx1 = pb[i0 * 3 + 3], cy1 = pb[i0 * 3 + 4], cz1 = pb[i0 * 3 + 5];

    #pragma unroll 2
    for (int j = lane; j < NPTS; j += 64) {
        const float px = pb[j * 3 + 0];
        const float py = pb[j * 3 + 1];
        const float pz = pb[j * 3 + 2];

        // strict IEEE mul/add (no contraction), matches numpy (x*x + y*y) + z*z
        const float dx0 = __fsub_rn(cx0, px);
        const float dy0 = __fsub_rn(cy0, py);
        const float dz0 = __fsub_rn(cz0, pz);
        const float d20 = __fadd_rn(__fadd_rn(__fmul_rn(dx0, dx0), __fmul_rn(dy0, dy0)),
                                    __fmul_rn(dz0, dz0));
        const float dx1 = __fsub_rn(cx1, px);
        const float dy1 = __fsub_rn(cy1, py);
        const float dz1 = __fsub_rn(cz1, pz);
        const float d21 = __fadd_rn(__fadd_rn(__fmul_rn(dx1, dx1), __fmul_rn(dy1, dy1)),
                                    __fmul_rn(dz1, dz1));

        const bool v0 = (d20 <= T1);
        const bool v1 = (d21 <= T1);
        if (v0 || v1) {                        // rare: ~20%/center per wave-iter
            const int av = __float2int_rn(ab[j] * SCALE);
            if (v0) {
                const int oct = (dx0 >= 0.0f ? 1 : 0) + (dy0 >= 0.0f ? 2 : 0)
                              + (dz0 >= 0.0f ? 4 : 0);
                const int cell = (d20 >= T2 ? 8 : 0) + oct;
                atomicAdd(&s_sum[w][0][cell], av);
                atomicAdd(&s_cnt[w][0][cell], 1);
            }
            if (v1) {
                const int oct = (dx1 >= 0.0f ? 1 : 0) + (dy1 >= 0.0f ? 2 : 0)
                              + (dz1 >= 0.0f ? 4 : 0);
                const int cell = (d21 >= T2 ? 8 : 0) + oct;
                atomicAdd(&s_sum[w][1][cell], av);
                atomicAdd(&s_cnt[w][1][cell], 1);
            }
        }
    }

    __syncthreads();

    if (lane < CPW * 16) {
        const int c = lane >> 4, q = lane & 15;
        const int          s = s_sum[w][c][q];
        const int          n = s_cnt[w][c][q];
        s_mean[w][c][q] = ((float)s * (1.0f / SCALE)) / (float)(n ? n : 1);
    }

    __syncthreads();

    if (lane < CPW * COUT) {                   // 18 active lanes
        const int c = (lane >= COUT) ? 1 : 0;
        const int o = lane - c * COUT;
        float acc = cb[o];
        #pragma unroll
        for (int q = 0; q < 16; ++q)
            acc = fmaf(s_mean[w][c][q], cw[o * 16 + q], acc);
        out[(size_t)(ci0 + c) * COUT + o] = acc;
    }
}

extern "C" void kernel_launch(void* const* d_in, const int* in_sizes, int n_in,
                              void* d_out, int out_size, void* d_ws, size_t ws_size,
                              hipStream_t stream) {
    const float* pts   = (const float*)d_in[0];  // [8,2048,3]
    const float* attrs = (const float*)d_in[1];  // [8,2048,1]
    const float* cw    = (const float*)d_in[2];  // [9,1,16]
    const float* cb    = (const float*)d_in[3];  // [9]
    float* out = (float*)d_out;                  // [8,2048,9]

    const int n_blocks = NC / (WPB * CPW);       // 2048 -> 8 blocks/CU, 8 waves/SIMD
    pconv_fused<<<n_blocks, 256, 0, stream>>>(pts, attrs, cw, cb, out);
}